// Round 1
// baseline (1236.718 us; speedup 1.0000x reference)
//
#include <hip/hip_runtime.h>

#define SENT 0x7f7f7f7f
#define NPTS_TOT 400000

// ---------------- voxelize: atomicMin cascade, K=8 smallest indices ----------
__global__ __launch_bounds__(256) void k_voxelize(const float* __restrict__ pts,
                                                  int* __restrict__ slots) {
  int i = blockIdx.x * 256 + threadIdx.x;
  if (i >= NPTS_TOT) return;
  float x = pts[i * 5 + 0];
  float y = pts[i * 5 + 1];
  float z = pts[i * 5 + 2];
  if (!(z >= -5.0f && z < 3.0f)) return;
  const float vsArr[4] = {0.4f, 0.8f, 1.6f, 3.2f};
  const int gArr[4] = {256, 128, 64, 32};
  const int ofsArr[4] = {0, 524288, 655360, 688128};
#pragma unroll
  for (int s = 0; s < 4; ++s) {
    float vs = vsArr[s];
    int G = gArr[s];
    float fx = floorf((x - (-51.2f)) / vs);
    float fy = floorf((y - (-51.2f)) / vs);
    if (!(fx >= 0.0f && fx < (float)G && fy >= 0.0f && fy < (float)G)) continue;
    int vid = (int)fy * G + (int)fx;
    int* sl = slots + ofsArr[s] + vid * 8;
    // prefilter: if all 8 slots are real and all < i, i can never be kept
    int mx = sl[0];
#pragma unroll
    for (int k = 1; k < 8; ++k) mx = max(mx, sl[k]);
    if (mx != SENT && i > mx) continue;
    int v = i;
#pragma unroll
    for (int k = 0; k < 8; ++k) {
      int old = atomicMin(&sl[k], v);
      if (old == SENT) break;   // filled an empty slot
      v = max(v, old);          // displaced (larger) value cascades on
    }
  }
}

// ------------- pass 1: pre-norm global stats (sum y, sum y^2, count) --------
__global__ __launch_bounds__(64) void k_stats_pre(
    const float* __restrict__ pts, const int* __restrict__ slots,
    const float* __restrict__ w_pre, const float* __restrict__ b_pre,
    float* __restrict__ stats, int G, int gshift, int V, float vs, int slot_ofs,
    int stats_ofs) {
  int lane = threadIdx.x;  // = output channel c
  float wcol[12];
#pragma unroll
  for (int r = 0; r < 12; ++r) wcol[r] = w_pre[r * 64 + lane];
  float bb = b_pre[lane];
  float vhalf = vs * 0.5f;
  float acc1 = 0.f, acc2 = 0.f;
  int accCnt = 0;
  for (int v = blockIdx.x; v < V; v += gridDim.x) {
    const int* sl = slots + slot_ofs + v * 8;
    int idx[8];
#pragma unroll
    for (int k = 0; k < 8; ++k) idx[k] = sl[k];
    int npts = 0;
#pragma unroll
    for (int k = 0; k < 8; ++k) npts += (idx[k] != SENT) ? 1 : 0;
    if (npts == 0) continue;
    float px[8], py[8], pz[8], f0[8], f1[8];
#pragma unroll
    for (int j = 0; j < 8; ++j)
      if (j < npts) {
        const float* p = pts + idx[j] * 5;
        px[j] = p[0]; py[j] = p[1]; pz[j] = p[2]; f0[j] = p[3]; f1[j] = p[4];
      }
    float nf = (float)npts;
    float cx = 0.f, cy = 0.f, cz = 0.f;
#pragma unroll
    for (int j = 0; j < 8; ++j)
      if (j < npts) { cx += px[j]; cy += py[j]; cz += pz[j]; }
    cx /= nf; cy /= nf; cz /= nf;
    float ax = (float)(v & (G - 1)) + vhalf;
    float ay = (float)(v >> gshift) + vhalf;
    float az = 4.0f;  // HEIGHT/2
#pragma unroll
    for (int j = 0; j < 8; ++j)
      if (j < npts) {
        float adx = px[j] - ax, ady = py[j] - ay, adz = pz[j] - az;
        float yraw = bb + f0[j] * wcol[0] + f1[j] * wcol[1] + adx * wcol[2] +
                     ady * wcol[3] + adz * wcol[4] + (px[j] - cx) * wcol[5] +
                     (py[j] - cy) * wcol[6] + (pz[j] - cz) * wcol[7] +
                     cx * wcol[8] + cy * wcol[9] + cz * wcol[10] + nf * wcol[11];
        acc1 += yraw;
        acc2 += yraw * yraw;
      }
    accCnt += npts;
  }
  float* sb = stats + stats_ofs;
  atomicAdd(&sb[lane], acc1);
  atomicAdd(&sb[64 + lane], acc2);
  if (lane == 0) atomicAdd(&sb[128], (float)accCnt);
}

// ------------- pass 2: normalized y, h, s, out, z_pre + post-norm stats -----
__global__ __launch_bounds__(64) void k_main(
    const float* __restrict__ pts, const int* __restrict__ slots,
    const float* __restrict__ kp, const float* __restrict__ w_pre,
    const float* __restrict__ b_pre, const float* __restrict__ g_pre,
    const float* __restrict__ beta_pre, const float* __restrict__ kpw,
    const float* __restrict__ w_post, const float* __restrict__ b_post,
    float* stats, float* __restrict__ zpre, int G, int gshift, int V, float vs,
    int slot_ofs, int stats_ofs, int zofs) {
  __shared__ float pd[8][5];
  __shared__ float hbuf[8][15];
  __shared__ float sbuf[15][64];
  __shared__ float obuf[64];
  int lane = threadIdx.x;
  float* sb = stats + stats_ofs;
  float cntf = fmaxf(sb[128], 1.0f);
  float ym = sb[lane] / cntf;
  float yvv = sb[64 + lane] / cntf - ym * ym;
  float den = sqrtf(yvv + 1e-5f);
  float gpre = g_pre[lane], bpre = beta_pre[lane];
  float wcol[12];
#pragma unroll
  for (int r = 0; r < 12; ++r) wcol[r] = w_pre[r * 64 + lane];
  float bb = b_pre[lane];
  float bpost = b_post[lane];
  float vhalf = vs * 0.5f;
  float zacc1 = 0.f, zacc2 = 0.f;
  for (int v = blockIdx.x; v < V; v += gridDim.x) {
    const int* sl = slots + slot_ofs + v * 8;
    int idx[8];
#pragma unroll
    for (int k = 0; k < 8; ++k) idx[k] = sl[k];
    int npts = 0;
#pragma unroll
    for (int k = 0; k < 8; ++k) npts += (idx[k] != SENT) ? 1 : 0;
    float z_out;
    if (npts == 0) {
      z_out = bpost;
    } else {
      float ax = (float)(v & (G - 1)) + vhalf;
      float ay = (float)(v >> gshift) + vhalf;
      float az = 4.0f;
      __syncthreads();  // previous iteration's LDS reads done
      if (lane < 40) {
        int j = lane / 5, r = lane % 5;
        if (j < npts) pd[j][r] = pts[idx[j] * 5 + r];
      }
      __syncthreads();
      int items = npts * 15;
      int myany = 0;
      for (int t = lane; t < items; t += 64) {
        int j = t / 15, k = t % 15;
        float dx = pd[j][0] - ax - kp[k * 3 + 0];
        float dy = pd[j][1] - ay - kp[k * 3 + 1];
        float dz = pd[j][2] - az - kp[k * 3 + 2];
        float dist = sqrtf(dx * dx + dy * dy + dz * dz + 1e-12f);
        float h = fmaxf(1.0f - dist, 0.0f);  // SIGMA = 1
        hbuf[j][k] = h;
        myany |= (h > 0.0f) ? 1 : 0;
      }
      __syncthreads();
      if (!__any(myany)) {
        z_out = bpost;  // s == 0 -> out == 0 -> z = b_post
      } else {
        float cx = 0.f, cy = 0.f, cz = 0.f;
#pragma unroll
        for (int j = 0; j < 8; ++j)
          if (j < npts) { cx += pd[j][0]; cy += pd[j][1]; cz += pd[j][2]; }
        float nf = (float)npts;
        cx /= nf; cy /= nf; cz /= nf;
        float s[15];
#pragma unroll
        for (int k = 0; k < 15; ++k) s[k] = 0.f;
#pragma unroll
        for (int j = 0; j < 8; ++j)
          if (j < npts) {
            float pxx = pd[j][0], pyy = pd[j][1], pzz = pd[j][2];
            float ff0 = pd[j][3], ff1 = pd[j][4];
            float adx = pxx - ax, ady = pyy - ay, adz = pzz - az;
            float yraw = bb + ff0 * wcol[0] + ff1 * wcol[1] + adx * wcol[2] +
                         ady * wcol[3] + adz * wcol[4] + (pxx - cx) * wcol[5] +
                         (pyy - cy) * wcol[6] + (pzz - cz) * wcol[7] +
                         cx * wcol[8] + cy * wcol[9] + cz * wcol[10] +
                         nf * wcol[11];
            float yn = fmaxf((yraw - ym) / den * gpre + bpre, 0.0f);
#pragma unroll
            for (int k = 0; k < 15; ++k) s[k] += hbuf[j][k] * yn;
          }
#pragma unroll
        for (int k = 0; k < 15; ++k) sbuf[k][lane] = s[k];
        __syncthreads();
        float od = 0.f;
        for (int k = 0; k < 15; ++k) {
#pragma unroll 8
          for (int c = 0; c < 64; ++c)
            od += sbuf[k][c] * kpw[(k * 64 + c) * 64 + lane];
        }
        obuf[lane] = od;
        __syncthreads();
        float zz = bpost;
#pragma unroll 8
        for (int c = 0; c < 64; ++c) zz += obuf[c] * w_post[c * 64 + lane];
        z_out = zz;
        __syncthreads();
      }
    }
    zpre[zofs + v * 64 + lane] = z_out;
    zacc1 += z_out;
    zacc2 += z_out * z_out;
  }
  atomicAdd(&sb[160 + lane], zacc1);
  atomicAdd(&sb[224 + lane], zacc2);
}

// ------------- pass 3: post-norm + relu + [v][c] -> [c][v] transpose --------
__global__ __launch_bounds__(256) void k_finalize(
    const float* __restrict__ zpre, const float* __restrict__ stats,
    const float* __restrict__ g_post, const float* __restrict__ beta_post,
    float* __restrict__ out, int V, int zofs, int oofs, int stats_ofs) {
  __shared__ float tile[64][65];
  int tid = threadIdx.x;
  int v0 = blockIdx.x * 64;
  const float* sb = stats + stats_ofs;
  float Vf = (float)V;
#pragma unroll
  for (int it = 0; it < 16; ++it) {
    int lin = it * 256 + tid;
    int vv = lin >> 6, d = lin & 63;
    tile[vv][d] = zpre[zofs + (v0 + vv) * 64 + d];
  }
  __syncthreads();
  int j = tid & 63;
  int dq = tid >> 6;
#pragma unroll
  for (int it = 0; it < 16; ++it) {
    int d = it * 4 + dq;
    float zm = sb[160 + d] / Vf;
    float zv = sb[224 + d] / Vf - zm * zm;
    float dn = sqrtf(zv + 1e-5f);
    float val = (tile[j][d] - zm) / dn * g_post[d] + beta_post[d];
    out[oofs + d * V + v0 + j] = fmaxf(val, 0.0f);
  }
}

extern "C" void kernel_launch(void* const* d_in, const int* in_sizes, int n_in,
                              void* d_out, int out_size, void* d_ws,
                              size_t ws_size, hipStream_t stream) {
  (void)in_sizes; (void)n_in; (void)out_size; (void)ws_size;
  const float* pts       = (const float*)d_in[0];
  const float* kp        = (const float*)d_in[1];
  const float* w_pre     = (const float*)d_in[2];
  const float* b_pre     = (const float*)d_in[3];
  const float* g_pre     = (const float*)d_in[4];
  const float* beta_pre  = (const float*)d_in[5];
  const float* kpw       = (const float*)d_in[6];
  const float* w_post    = (const float*)d_in[7];
  const float* b_post    = (const float*)d_in[8];
  const float* g_post    = (const float*)d_in[9];
  const float* beta_post = (const float*)d_in[10];
  float* out = (float*)d_out;

  int* slots   = (int*)d_ws;                              // 696320 ints
  float* stats = (float*)((char*)d_ws + 2785280);         // 4 x 320 floats
  float* zpre  = (float*)((char*)d_ws + 2790400);         // 87040 x 64 floats

  hipMemsetAsync(slots, 0x7f, 696320 * 4, stream);
  hipMemsetAsync(stats, 0, 1280 * 4, stream);

  k_voxelize<<<(NPTS_TOT + 255) / 256, 256, 0, stream>>>(pts, slots);

  const int Gs[4]   = {256, 128, 64, 32};
  const int sh[4]   = {8, 7, 6, 5};
  const float vss[4] = {0.4f, 0.8f, 1.6f, 3.2f};
  const int sofs[4] = {0, 524288, 655360, 688128};
  const int vofs[4] = {0, 65536, 81920, 86016};

  for (int s = 0; s < 4; ++s) {
    int V = Gs[s] * Gs[s];
    int grid = V < 4096 ? V : 4096;
    k_stats_pre<<<grid, 64, 0, stream>>>(pts, slots, w_pre, b_pre, stats, Gs[s],
                                         sh[s], V, vss[s], sofs[s], s * 320);
  }
  for (int s = 0; s < 4; ++s) {
    int V = Gs[s] * Gs[s];
    int grid = V < 4096 ? V : 4096;
    k_main<<<grid, 64, 0, stream>>>(pts, slots, kp, w_pre, b_pre, g_pre,
                                    beta_pre, kpw, w_post, b_post, stats, zpre,
                                    Gs[s], sh[s], V, vss[s], sofs[s], s * 320,
                                    vofs[s] * 64);
  }
  for (int s = 0; s < 4; ++s) {
    int V = Gs[s] * Gs[s];
    k_finalize<<<V / 64, 256, 0, stream>>>(zpre, stats, g_post, beta_post, out,
                                           V, vofs[s] * 64, vofs[s] * 64,
                                           s * 320);
  }
}